// Round 12
// baseline (283.752 us; speedup 1.0000x reference)
//
#include <hip/hip_runtime.h>
#include <hip/hip_bf16.h>
#include <stdint.h>

// ---- problem constants ----
#define BDIM 2
#define SDIM 2048
#define HID 2048
#define NH 16
#define NKV 4
#define HD 128
#define QSZ 2048
#define KVSZ 512
#define QKVW 3072          // QSZ + 2*KVSZ
#define TOK (BDIM*SDIM)    // 4096

typedef __attribute__((ext_vector_type(8))) short bf16x8;
typedef __attribute__((ext_vector_type(4))) float f32x4;
typedef __attribute__((ext_vector_type(16))) float f32x16;

__device__ __forceinline__ short f2bf(float f) {
  return (short)__bfloat16_as_ushort(__float2bfloat16(f));   // RNE; pairs fuse to v_cvt_pk_bf16_f32
}
__device__ __forceinline__ float bf2f(short s) {
  return __uint_as_float(((uint32_t)(uint16_t)s) << 16);
}

// 2^x via the HW transcendental (no __exp2f in this toolchain's headers)
__device__ __forceinline__ float exp2_fast(float x) {
  float r;
  asm("v_exp_f32 %0, %1" : "=v"(r) : "v"(x));
  return r;
}

// sin/cos with input in REVOLUTIONS (v_sin/v_cos native domain; fract-reduce first)
__device__ __forceinline__ void sincos_rev(float rev, float* sn, float* cs) {
  float fr, s, c;
  asm("v_fract_f32 %0, %1" : "=v"(fr) : "v"(rev));
  asm("v_sin_f32 %0, %1" : "=v"(s) : "v"(fr));
  asm("v_cos_f32 %0, %1" : "=v"(c) : "v"(fr));
  *sn = s; *cs = c;
}

__device__ __forceinline__ void gload_lds16(const void* g, void* lds) {
  __builtin_amdgcn_global_load_lds(
      (const __attribute__((address_space(1))) void*)g,
      (__attribute__((address_space(3))) void*)lds, 16, 0, 0);
}

// ---- elementwise f32 -> bf16 ----
__global__ __launch_bounds__(256) void k_cvt_bf16(const float* __restrict__ in,
                                                  short* __restrict__ out, int n) {
  int i = (blockIdx.x * 256 + threadIdx.x) * 4;
  if (i >= n) return;
  float4 v = *(const float4*)(in + i);
  short4 o; o.x = f2bf(v.x); o.y = f2bf(v.y); o.z = f2bf(v.z); o.w = f2bf(v.w);
  *(short4*)(out + i) = o;
}

// ---- transpose + convert: in f32 [R][C] -> out bf16 [C][R] ----
__global__ __launch_bounds__(256) void k_transpose_cvt(const float* __restrict__ in,
                                                       short* __restrict__ out,
                                                       int R, int C) {
  __shared__ short tile[64][65];
  int k0 = blockIdx.y * 64;       // input row block
  int n0 = blockIdx.x * 64;       // input col block
  int t = threadIdx.x;
#pragma unroll
  for (int i = 0; i < 16; ++i) {
    int idx = i * 256 + t;
    int kk = idx >> 6, nn = idx & 63;
    tile[kk][nn] = f2bf(in[(size_t)(k0 + kk) * C + n0 + nn]);
  }
  __syncthreads();
#pragma unroll
  for (int i = 0; i < 16; ++i) {
    int idx = i * 256 + t;
    int nn = idx >> 6, kk = idx & 63;
    out[(size_t)(n0 + nn) * R + k0 + kk] = tile[kk][nn];
  }
}

// ---- bf16 GEMM: C[M][N] f32 = A[M][K] * Bt[N][K]^T  (m97 structure) ----
__global__ __launch_bounds__(256) void k_gemm_bf16(const short* __restrict__ A,
                                                   const short* __restrict__ Bt,
                                                   float* __restrict__ C,
                                                   int M, int N, int K) {
  __shared__ char lds[128 * 32 * 2 * 2];   // As 8KB + Bs 8KB
  char* As = lds;
  char* Bs = lds + 8192;
  const int tid = threadIdx.x;
  const int w = tid >> 6, l = tid & 63;
  const int lq = l & 15, g = l >> 4;
  const int m0 = blockIdx.y * 128, n0 = blockIdx.x * 128;
  const int wm = (w >> 1) * 64, wn = (w & 1) * 64;
  f32x4 acc[4][4] = {};

  const int nk = K >> 5;
  for (int kt = 0; kt < nk; ++kt) {
    const int k0 = kt * 32;
#pragma unroll
    for (int i = 0; i < 2; ++i) {
      int ch = (w + 4 * i) * 64 + l;          // 16B chunk id in tile
      int r = ch >> 2, cc = ch & 3;
      int gc = cc ^ ((r >> 1) & 3);           // XOR swizzle (involution)
      gload_lds16(A + (size_t)(m0 + r) * K + k0 + gc * 8, As + (w + 4 * i) * 1024);
      gload_lds16(Bt + (size_t)(n0 + r) * K + k0 + gc * 8, Bs + (w + 4 * i) * 1024);
    }
    __syncthreads();
    bf16x8 af[4], bfr[4];
#pragma unroll
    for (int mi = 0; mi < 4; ++mi) {
      int row = wm + mi * 16 + lq;
      af[mi] = *(const bf16x8*)(As + row * 64 + ((g ^ ((row >> 1) & 3)) * 16));
    }
#pragma unroll
    for (int ni = 0; ni < 4; ++ni) {
      int row = wn + ni * 16 + lq;
      bfr[ni] = *(const bf16x8*)(Bs + row * 64 + ((g ^ ((row >> 1) & 3)) * 16));
    }
#pragma unroll
    for (int mi = 0; mi < 4; ++mi)
#pragma unroll
      for (int ni = 0; ni < 4; ++ni)
        acc[mi][ni] = __builtin_amdgcn_mfma_f32_16x16x32_bf16(af[mi], bfr[ni],
                                                              acc[mi][ni], 0, 0, 0);
    __syncthreads();
  }
#pragma unroll
  for (int mi = 0; mi < 4; ++mi)
#pragma unroll
    for (int ni = 0; ni < 4; ++ni)
#pragma unroll
      for (int r = 0; r < 4; ++r) {
        int row = m0 + wm + mi * 16 + 4 * g + r;
        int col = n0 + wn + ni * 16 + lq;
        C[(size_t)row * N + col] = acc[mi][ni][r];
      }
}

// ---- fused QKV GEMM + RoPE + bf16 layout (verified rounds 8/11) ----
__global__ __launch_bounds__(256) void k_gemm_qkv_rope(const short* __restrict__ A,
                                                       const short* __restrict__ Bt,
                                                       const int* __restrict__ pos,
                                                       short* __restrict__ Qh,
                                                       short* __restrict__ Kh,
                                                       short* __restrict__ VT) {
  __shared__ char lds[128 * 32 * 2 * 2];   // As 8KB + Bs 8KB
  char* As = lds;
  char* Bs = lds + 8192;
  const int tid = threadIdx.x;
  const int w = tid >> 6, l = tid & 63;
  const int lq = l & 15, g = l >> 4;
  const int m0 = blockIdx.y * 128, n0 = blockIdx.x * 128;
  const int K = HID;
  f32x4 acc[2][8] = {};

  const int nk = K >> 5;
  for (int kt = 0; kt < nk; ++kt) {
    const int k0 = kt * 32;
#pragma unroll
    for (int i = 0; i < 2; ++i) {
      int ch = (w + 4 * i) * 64 + l;
      int r = ch >> 2, cc = ch & 3;
      int gc = cc ^ ((r >> 1) & 3);
      gload_lds16(A + (size_t)(m0 + r) * K + k0 + gc * 8, As + (w + 4 * i) * 1024);
      gload_lds16(Bt + (size_t)(n0 + r) * K + k0 + gc * 8, Bs + (w + 4 * i) * 1024);
    }
    __syncthreads();
    bf16x8 af[2], bfr[8];
#pragma unroll
    for (int mi = 0; mi < 2; ++mi) {
      int row = w * 32 + mi * 16 + lq;
      af[mi] = *(const bf16x8*)(As + row * 64 + ((g ^ ((row >> 1) & 3)) * 16));
    }
#pragma unroll
    for (int ni = 0; ni < 8; ++ni) {
      int row = ni * 16 + lq;
      bfr[ni] = *(const bf16x8*)(Bs + row * 64 + ((g ^ ((row >> 1) & 3)) * 16));
    }
#pragma unroll
    for (int mi = 0; mi < 2; ++mi)
#pragma unroll
      for (int ni = 0; ni < 8; ++ni)
        acc[mi][ni] = __builtin_amdgcn_mfma_f32_16x16x32_bf16(af[mi], bfr[ni],
                                                              acc[mi][ni], 0, 0, 0);
    __syncthreads();
  }

  const int hx = blockIdx.x;
  const int b = m0 >> 11;                   // 128-row tile lies in one batch
  if (hx < 20) {
    const float qscale = 0.12751743920f;    // log2(e)/sqrt(128)
    const float sc = (hx < 16) ? qscale : 1.0f;
    short* dst = (hx < 16) ? (Qh + (size_t)(b * NH + hx) * SDIM * HD)
                           : (Kh + (size_t)(b * NKV + (hx - 16)) * SDIM * HD);
    // invf_rev[ni] = 10000^(-(ni*16+lq)/64) / (2*pi)
    float invf[4];
#pragma unroll
    for (int ni = 0; ni < 4; ++ni)
      invf[ni] = 0.15915494309f *
                 exp2_fast(-(float)(ni * 16 + lq) * (13.287712379549449f / 64.0f));
#pragma unroll
    for (int mi = 0; mi < 2; ++mi)
#pragma unroll
      for (int r = 0; r < 4; ++r) {
        int row = m0 + w * 32 + mi * 16 + 4 * g + r;
        int s = row & (SDIM - 1);
        float p = (float)pos[row];
        size_t hb = (size_t)s * HD;
#pragma unroll
        for (int ni = 0; ni < 4; ++ni) {
          float sn, cs;
          sincos_rev(p * invf[ni], &sn, &cs);
          float x1 = acc[mi][ni][r], x2 = acc[mi][ni + 4][r];
          dst[hb + ni * 16 + lq] = f2bf((x1 * cs - x2 * sn) * sc);
          dst[hb + ni * 16 + lq + 64] = f2bf((x2 * cs + x1 * sn) * sc);
        }
      }
  } else {
    const int hv = hx - 20;
    const int s00 = (m0 & (SDIM - 1)) + w * 32;
#pragma unroll
    for (int mi = 0; mi < 2; ++mi)
#pragma unroll
      for (int ni = 0; ni < 8; ++ni) {
        int d = ni * 16 + lq;
        int s0 = s00 + mi * 16 + 4 * g;
        size_t vb = ((size_t)(b * NKV + hv) * HD + d) * SDIM + s0;
        short4 ov;
        ov.x = f2bf(acc[mi][ni][0]); ov.y = f2bf(acc[mi][ni][1]);
        ov.z = f2bf(acc[mi][ni][2]); ov.w = f2bf(acc[mi][ni][3]);
        *(short4*)(VT + vb) = ov;
      }
  }
}

// ---- flash attention, causal GQA, INTRA-BLOCK kv-split x2 ----
// 512 threads = 8 waves: waves 0-3 = 4 q-subchunks x low kv half, waves 4-7 =
// same q x high kv half. Per-half double-buffered KVBLK=32 LDS staging (64KB).
// 4096 waves total -> 4 waves/SIMD (vs 2 before). Partials merged in LDS
// (bf16 O~ + f32 m,l): hi waves write, lo waves weight-combine exp2(mi-M).
// Fully-masked hi partials get weight exactly 0. Per-tile body identical to
// the verified round-6/10 code (log2 softmax, defer-max, cvt_pk pack, setprio).
__global__ __launch_bounds__(512, 4) void k_attn(const short* __restrict__ Qh,
                                                 const short* __restrict__ Kh,
                                                 const short* __restrict__ VT,
                                                 short* __restrict__ attn, int S) {
  __shared__ char lds[65536];   // [sp][buf][16KB: K 8KB + V 8KB]; merge area reuses
  const int tid = threadIdx.x;
  const int w = tid >> 6, l = tid & 63;
  const int l31 = l & 31, hi = l >> 5;
  const int wq = w & 3;                     // q-subchunk
  const int sp = w >> 2;                    // kv half (0 lo, 1 hi)
  const int nqc = S / 128;                  // 16
  const int bid = blockIdx.x;
  const int b = bid / (NH * nqc);
  const int rem = bid % (NH * nqc);
  const int h = rem / nqc;
  const int qc = nqc - 1 - (rem % nqc);     // long blocks first
  const int q0 = qc * 128 + wq * 32;
  const int kvh = h >> 2;
  const short* Qp = Qh + (size_t)(b * NH + h) * S * HD;
  const short* Kp = Kh + (size_t)(b * NKV + kvh) * S * HD;
  const short* Vp = VT + (size_t)(b * NKV + kvh) * HD * S;
  char* base = lds + sp * 32768;

  // Q B-frags: col=l31=q, k = kc*16 + hi*8 + e
  bf16x8 qf[8];
#pragma unroll
  for (int kc = 0; kc < 8; ++kc)
    qf[kc] = *(const bf16x8*)(Qp + (size_t)(q0 + l31) * HD + kc * 16 + hi * 8);

  f32x16 o[4] = {};   // O^T block d0: row=d-rel=(r&3)+8*(r>>2)+4*hi, col=q=l31
  float mrun = -1e30f, lrun = 0.f;
  const int qabs = q0 + l31;
  const int halfT = qc * 2 + 2;             // 32-kv tiles per half (uniform)
  const int cbeg = sp * halfT;

  // STAGE by this half's 4 waves (256 threads): K 8KB (512 chunks) + V 8KB.
  // K [kr=id>>4][c16=id&15] swz c16^(kr&15); V [vr=id>>2][c4=id&3] swz
  // c4^((vr>>1)&3). LDS dest wave-uniform (rule #21).
#define STAGE(bufi, c0_)                                                          \
  {                                                                               \
    char* Kb = base + (bufi) * 16384;                                             \
    char* Vb = Kb + 8192;                                                         \
    _Pragma("unroll")                                                             \
    for (int i = 0; i < 2; ++i) {                                                 \
      int id = (i * 4 + wq) * 64 + l;                                             \
      int kr = id >> 4, c16 = id & 15;                                            \
      gload_lds16(Kp + (size_t)((c0_) + kr) * HD + ((c16 ^ (kr & 15)) * 8),       \
                  Kb + (i * 4 + wq) * 1024);                                      \
      int vr = id >> 2, c4 = id & 3;                                              \
      gload_lds16(Vp + (size_t)vr * S + (c0_) + ((c4 ^ ((vr >> 1) & 3)) * 8),     \
                  Vb + (i * 4 + wq) * 1024);                                      \
    }                                                                             \
  }

  STAGE(0, cbeg * 32);
  asm volatile("s_waitcnt vmcnt(0)" ::: "memory");
  __builtin_amdgcn_s_barrier();

  for (int t = 0; t < halfT; ++t) {
    const int c0 = (cbeg + t) * 32;
    const int cur = t & 1;
    if (t + 1 < halfT) STAGE(cur ^ 1, c0 + 32);
    const char* Ks = base + cur * 16384;
    const char* Vs = Ks + 8192;

    // --- QK^T from LDS (one 32-kv subtile) ---
    f32x16 st = {};
    __builtin_amdgcn_s_setprio(1);
#pragma unroll
    for (int kc = 0; kc < 8; ++kc) {
      bf16x8 kf = *(const bf16x8*)(Ks + l31 * 256 + (((kc * 2 + hi) ^ (l31 & 15)) * 16));
      st = __builtin_amdgcn_mfma_f32_32x32x16_bf16(kf, qf[kc], st, 0, 0, 0);
    }
    __builtin_amdgcn_s_setprio(0);
    // --- mask (boundary tiles only) + online softmax (log2 domain) ---
    float tmax = -1e30f;
    if (c0 + 32 <= q0) {                    // interior: no lane needs masking
#pragma unroll
      for (int r = 0; r < 16; ++r) tmax = fmaxf(tmax, st[r]);
    } else {
#pragma unroll
      for (int r = 0; r < 16; ++r) {
        int kv = c0 + (r & 3) + 8 * (r >> 2) + 4 * hi;
        float sv = (kv <= qabs) ? st[r] : -1e30f;
        st[r] = sv;
        tmax = fmaxf(tmax, sv);
      }
    }
    tmax = fmaxf(tmax, __shfl_xor(tmax, 32));
    if (!__all(tmax - mrun <= 8.0f)) {      // defer-max
      float mnew = fmaxf(mrun, tmax);
      float fac = exp2_fast(mrun - mnew);
      lrun *= fac;
#pragma unroll
      for (int d0 = 0; d0 < 4; ++d0) o[d0] = o[d0] * fac;
      mrun = mnew;
    }
    float sum = 0.f;
#pragma unroll
    for (int r = 0; r < 16; ++r) {
      float e = exp2_fast(st[r] - mrun);
      st[r] = e;
      sum += e;
    }
    sum += __shfl_xor(sum, 32);
    lrun += sum;
    // --- P -> B-frags (packed-word lane-half exchange) + PV from LDS V ---
    __builtin_amdgcn_s_setprio(1);
#pragma unroll
    for (int j = 0; j < 2; ++j) {
      uint32_t W0 = (uint32_t)(uint16_t)f2bf(st[8 * j + 0]) |
                    ((uint32_t)(uint16_t)f2bf(st[8 * j + 1]) << 16);
      uint32_t W1 = (uint32_t)(uint16_t)f2bf(st[8 * j + 2]) |
                    ((uint32_t)(uint16_t)f2bf(st[8 * j + 3]) << 16);
      uint32_t W2 = (uint32_t)(uint16_t)f2bf(st[8 * j + 4]) |
                    ((uint32_t)(uint16_t)f2bf(st[8 * j + 5]) << 16);
      uint32_t W3 = (uint32_t)(uint16_t)f2bf(st[8 * j + 6]) |
                    ((uint32_t)(uint16_t)f2bf(st[8 * j + 7]) << 16);
      uint32_t Y0 = __shfl_xor(hi ? W0 : W2, 32);
      uint32_t Y1 = __shfl_xor(hi ? W1 : W3, 32);
      union { uint32_t u[4]; bf16x8 v; } pu;
      pu.u[0] = hi ? Y0 : W0;
      pu.u[1] = hi ? Y1 : W1;
      pu.u[2] = hi ? W2 : Y0;
      pu.u[3] = hi ? W3 : Y1;
#pragma unroll
      for (int d0 = 0; d0 < 4; ++d0) {
        int vr = d0 * 32 + l31;
        bf16x8 vf = *(const bf16x8*)(Vs + vr * 64 + (((j * 2 + hi) ^ ((vr >> 1) & 3)) * 16));
        o[d0] = __builtin_amdgcn_mfma_f32_32x32x16_bf16(vf, pu.v, o[d0], 0, 0, 0);
      }
    }
    __builtin_amdgcn_s_setprio(0);
    asm volatile("s_waitcnt vmcnt(0)" ::: "memory");
    __builtin_amdgcn_s_barrier();
  }
#undef STAGE

  // ---- merge the two kv halves in LDS (KV buffers are dead now) ----
  // hi wave lane: 64 bf16 partials at wq*9216 + l*144 (16B-aligned chunks,
  // chunk k = d0*2+gh holds o[d0][gh*8..gh*8+7]); (m,l) f32 at 40960+.
  if (sp == 1) {
    char* ob = lds + wq * 9216 + l * 144;
#pragma unroll
    for (int d0 = 0; d0 < 4; ++d0)
#pragma unroll
      for (int gh = 0; gh < 2; ++gh) {
        short t8[8];
#pragma unroll
        for (int j = 0; j < 8; ++j) t8[j] = f2bf(o[d0][gh * 8 + j]);
        *(bf16x8*)(ob + (d0 * 2 + gh) * 16) = *(bf16x8*)t8;
      }
    if (hi == 0) {
      float2 t; t.x = mrun; t.y = lrun;
      *(float2*)(lds + 40960 + wq * 256 + l31 * 8) = t;
    }
  }
  __syncthreads();
  if (sp == 0) {
    float2 m2 = *(const float2*)(lds + 40960 + wq * 256 + l31 * 8);
    float M = fmaxf(mrun, m2.x);
    float a1 = exp2_fast(mrun - M), a2 = exp2_fast(m2.x - M);
    float denom = lrun * a1 + m2.y * a2;
    float f1 = a1 / denom, f2v = a2 / denom;
    const char* ob = lds + wq * 9216 + l * 144;
    size_t rowb = (size_t)(b * S + q0 + l31) * QSZ + h * HD;
#pragma unroll
    for (int d0 = 0; d0 < 4; ++d0)
#pragma unroll
      for (int gq = 0; gq < 4; ++gq) {      // drel group: 8*gq + 4*hi + (0..3)
        bf16x8 v2 = *(const bf16x8*)(ob + (d0 * 2 + (gq >> 1)) * 16);
        int e0 = (gq & 1) * 4;
        short4 ov;
        ov.x = f2bf(o[d0][4 * gq + 0] * f1 + bf2f(v2[e0 + 0]) * f2v);
        ov.y = f2bf(o[d0][4 * gq + 1] * f1 + bf2f(v2[e0 + 1]) * f2v);
        ov.z = f2bf(o[d0][4 * gq + 2] * f1 + bf2f(v2[e0 + 2]) * f2v);
        ov.w = f2bf(o[d0][4 * gq + 3] * f1 + bf2f(v2[e0 + 3]) * f2v);
        *(short4*)(attn + rowb + d0 * 32 + 8 * gq + 4 * hi) = ov;
      }
  }
}

extern "C" void kernel_launch(void* const* d_in, const int* in_sizes, int n_in,
                              void* d_out, int out_size, void* d_ws, size_t ws_size,
                              hipStream_t stream) {
  const int* positions = (const int*)d_in[0];
  const float* hidden = (const float*)d_in[1];
  const float* w_qkv = (const float*)d_in[2];
  const float* w_o = (const float*)d_in[3];
  float* out = (float*)d_out;

  char* ws = (char*)d_ws;
  short* X     = (short*)(ws);                    // 4096x2048 bf16
  short* WqkvT = (short*)(ws + 16777216);         // 3072x2048 bf16
  short* WoT   = (short*)(ws + 29360128);         // 2048x2048 bf16
  short* Qh    = (short*)(ws + 88080384);         // [2][16][2048][128]
  short* Kh    = (short*)(ws + 104857600);        // [2][4][2048][128]
  short* VT    = (short*)(ws + 109051904);        // [2][4][128][2048]
  short* ATT   = (short*)(ws + 113246208);        // [4096][2048] bf16

  k_cvt_bf16<<<8192, 256, 0, stream>>>(hidden, X, TOK * HID);
  k_transpose_cvt<<<dim3(QKVW / 64, HID / 64), 256, 0, stream>>>(w_qkv, WqkvT, HID, QKVW);
  k_transpose_cvt<<<dim3(HID / 64, QSZ / 64), 256, 0, stream>>>(w_o, WoT, QSZ, HID);
  k_gemm_qkv_rope<<<dim3(QKVW / 128, TOK / 128), 256, 0, stream>>>(X, WqkvT, positions,
                                                                   Qh, Kh, VT);
  k_attn<<<BDIM * NH * (SDIM / 128), 512, 0, stream>>>(Qh, Kh, VT, ATT, SDIM);
  k_gemm_bf16<<<dim3(HID / 128, TOK / 128), 256, 0, stream>>>(ATT, WoT, out, TOK, HID, QSZ);
}

// Round 13
// 235.810 us; speedup vs baseline: 1.2033x; 1.2033x over previous
//
#include <hip/hip_runtime.h>
#include <hip/hip_bf16.h>
#include <stdint.h>

// ---- problem constants ----
#define BDIM 2
#define SDIM 2048
#define HID 2048
#define NH 16
#define NKV 4
#define HD 128
#define QSZ 2048
#define KVSZ 512
#define QKVW 3072          // QSZ + 2*KVSZ
#define TOK (BDIM*SDIM)    // 4096

typedef __attribute__((ext_vector_type(8))) short bf16x8;
typedef __attribute__((ext_vector_type(4))) float f32x4;
typedef __attribute__((ext_vector_type(16))) float f32x16;

__device__ __forceinline__ short f2bf(float f) {
  return (short)__bfloat16_as_ushort(__float2bfloat16(f));   // RNE; pairs fuse to v_cvt_pk_bf16_f32
}
__device__ __forceinline__ float bf2f(short s) {
  return __uint_as_float(((uint32_t)(uint16_t)s) << 16);
}

// 2^x via the HW transcendental (no __exp2f in this toolchain's headers)
__device__ __forceinline__ float exp2_fast(float x) {
  float r;
  asm("v_exp_f32 %0, %1" : "=v"(r) : "v"(x));
  return r;
}

// sin/cos with input in REVOLUTIONS (v_sin/v_cos native domain; fract-reduce first)
__device__ __forceinline__ void sincos_rev(float rev, float* sn, float* cs) {
  float fr, s, c;
  asm("v_fract_f32 %0, %1" : "=v"(fr) : "v"(rev));
  asm("v_sin_f32 %0, %1" : "=v"(s) : "v"(fr));
  asm("v_cos_f32 %0, %1" : "=v"(c) : "v"(fr));
  *sn = s; *cs = c;
}

__device__ __forceinline__ void gload_lds16(const void* g, void* lds) {
  __builtin_amdgcn_global_load_lds(
      (const __attribute__((address_space(1))) void*)g,
      (__attribute__((address_space(3))) void*)lds, 16, 0, 0);
}

// ---- elementwise f32 -> bf16 ----
__global__ __launch_bounds__(256) void k_cvt_bf16(const float* __restrict__ in,
                                                  short* __restrict__ out, int n) {
  int i = (blockIdx.x * 256 + threadIdx.x) * 4;
  if (i >= n) return;
  float4 v = *(const float4*)(in + i);
  short4 o; o.x = f2bf(v.x); o.y = f2bf(v.y); o.z = f2bf(v.z); o.w = f2bf(v.w);
  *(short4*)(out + i) = o;
}

// ---- transpose + convert: in f32 [R][C] -> out bf16 [C][R] ----
__global__ __launch_bounds__(256) void k_transpose_cvt(const float* __restrict__ in,
                                                       short* __restrict__ out,
                                                       int R, int C) {
  __shared__ short tile[64][65];
  int k0 = blockIdx.y * 64;       // input row block
  int n0 = blockIdx.x * 64;       // input col block
  int t = threadIdx.x;
#pragma unroll
  for (int i = 0; i < 16; ++i) {
    int idx = i * 256 + t;
    int kk = idx >> 6, nn = idx & 63;
    tile[kk][nn] = f2bf(in[(size_t)(k0 + kk) * C + n0 + nn]);
  }
  __syncthreads();
#pragma unroll
  for (int i = 0; i < 16; ++i) {
    int idx = i * 256 + t;
    int nn = idx >> 6, kk = idx & 63;
    out[(size_t)(n0 + nn) * R + k0 + kk] = tile[kk][nn];
  }
}

// ---- bf16 GEMM: C[M][N] f32 = A[M][K] * Bt[N][K]^T  (m97 structure) ----
__global__ __launch_bounds__(256) void k_gemm_bf16(const short* __restrict__ A,
                                                   const short* __restrict__ Bt,
                                                   float* __restrict__ C,
                                                   int M, int N, int K) {
  __shared__ char lds[128 * 32 * 2 * 2];   // As 8KB + Bs 8KB
  char* As = lds;
  char* Bs = lds + 8192;
  const int tid = threadIdx.x;
  const int w = tid >> 6, l = tid & 63;
  const int lq = l & 15, g = l >> 4;
  const int m0 = blockIdx.y * 128, n0 = blockIdx.x * 128;
  const int wm = (w >> 1) * 64, wn = (w & 1) * 64;
  f32x4 acc[4][4] = {};

  const int nk = K >> 5;
  for (int kt = 0; kt < nk; ++kt) {
    const int k0 = kt * 32;
#pragma unroll
    for (int i = 0; i < 2; ++i) {
      int ch = (w + 4 * i) * 64 + l;          // 16B chunk id in tile
      int r = ch >> 2, cc = ch & 3;
      int gc = cc ^ ((r >> 1) & 3);           // XOR swizzle (involution)
      gload_lds16(A + (size_t)(m0 + r) * K + k0 + gc * 8, As + (w + 4 * i) * 1024);
      gload_lds16(Bt + (size_t)(n0 + r) * K + k0 + gc * 8, Bs + (w + 4 * i) * 1024);
    }
    __syncthreads();
    bf16x8 af[4], bfr[4];
#pragma unroll
    for (int mi = 0; mi < 4; ++mi) {
      int row = wm + mi * 16 + lq;
      af[mi] = *(const bf16x8*)(As + row * 64 + ((g ^ ((row >> 1) & 3)) * 16));
    }
#pragma unroll
    for (int ni = 0; ni < 4; ++ni) {
      int row = wn + ni * 16 + lq;
      bfr[ni] = *(const bf16x8*)(Bs + row * 64 + ((g ^ ((row >> 1) & 3)) * 16));
    }
#pragma unroll
    for (int mi = 0; mi < 4; ++mi)
#pragma unroll
      for (int ni = 0; ni < 4; ++ni)
        acc[mi][ni] = __builtin_amdgcn_mfma_f32_16x16x32_bf16(af[mi], bfr[ni],
                                                              acc[mi][ni], 0, 0, 0);
    __syncthreads();
  }
#pragma unroll
  for (int mi = 0; mi < 4; ++mi)
#pragma unroll
    for (int ni = 0; ni < 4; ++ni)
#pragma unroll
      for (int r = 0; r < 4; ++r) {
        int row = m0 + wm + mi * 16 + 4 * g + r;
        int col = n0 + wn + ni * 16 + lq;
        C[(size_t)row * N + col] = acc[mi][ni][r];
      }
}

// ---- fused QKV GEMM + RoPE + bf16 layout (verified rounds 8/11) ----
__global__ __launch_bounds__(256) void k_gemm_qkv_rope(const short* __restrict__ A,
                                                       const short* __restrict__ Bt,
                                                       const int* __restrict__ pos,
                                                       short* __restrict__ Qh,
                                                       short* __restrict__ Kh,
                                                       short* __restrict__ VT) {
  __shared__ char lds[128 * 32 * 2 * 2];   // As 8KB + Bs 8KB
  char* As = lds;
  char* Bs = lds + 8192;
  const int tid = threadIdx.x;
  const int w = tid >> 6, l = tid & 63;
  const int lq = l & 15, g = l >> 4;
  const int m0 = blockIdx.y * 128, n0 = blockIdx.x * 128;
  const int K = HID;
  f32x4 acc[2][8] = {};

  const int nk = K >> 5;
  for (int kt = 0; kt < nk; ++kt) {
    const int k0 = kt * 32;
#pragma unroll
    for (int i = 0; i < 2; ++i) {
      int ch = (w + 4 * i) * 64 + l;
      int r = ch >> 2, cc = ch & 3;
      int gc = cc ^ ((r >> 1) & 3);
      gload_lds16(A + (size_t)(m0 + r) * K + k0 + gc * 8, As + (w + 4 * i) * 1024);
      gload_lds16(Bt + (size_t)(n0 + r) * K + k0 + gc * 8, Bs + (w + 4 * i) * 1024);
    }
    __syncthreads();
    bf16x8 af[2], bfr[8];
#pragma unroll
    for (int mi = 0; mi < 2; ++mi) {
      int row = w * 32 + mi * 16 + lq;
      af[mi] = *(const bf16x8*)(As + row * 64 + ((g ^ ((row >> 1) & 3)) * 16));
    }
#pragma unroll
    for (int ni = 0; ni < 8; ++ni) {
      int row = ni * 16 + lq;
      bfr[ni] = *(const bf16x8*)(Bs + row * 64 + ((g ^ ((row >> 1) & 3)) * 16));
    }
#pragma unroll
    for (int mi = 0; mi < 2; ++mi)
#pragma unroll
      for (int ni = 0; ni < 8; ++ni)
        acc[mi][ni] = __builtin_amdgcn_mfma_f32_16x16x32_bf16(af[mi], bfr[ni],
                                                              acc[mi][ni], 0, 0, 0);
    __syncthreads();
  }

  const int hx = blockIdx.x;
  const int b = m0 >> 11;                   // 128-row tile lies in one batch
  if (hx < 20) {
    const float qscale = 0.12751743920f;    // log2(e)/sqrt(128)
    const float sc = (hx < 16) ? qscale : 1.0f;
    short* dst = (hx < 16) ? (Qh + (size_t)(b * NH + hx) * SDIM * HD)
                           : (Kh + (size_t)(b * NKV + (hx - 16)) * SDIM * HD);
    // invf_rev[ni] = 10000^(-(ni*16+lq)/64) / (2*pi)
    float invf[4];
#pragma unroll
    for (int ni = 0; ni < 4; ++ni)
      invf[ni] = 0.15915494309f *
                 exp2_fast(-(float)(ni * 16 + lq) * (13.287712379549449f / 64.0f));
#pragma unroll
    for (int mi = 0; mi < 2; ++mi)
#pragma unroll
      for (int r = 0; r < 4; ++r) {
        int row = m0 + w * 32 + mi * 16 + 4 * g + r;
        int s = row & (SDIM - 1);
        float p = (float)pos[row];
        size_t hb = (size_t)s * HD;
#pragma unroll
        for (int ni = 0; ni < 4; ++ni) {
          float sn, cs;
          sincos_rev(p * invf[ni], &sn, &cs);
          float x1 = acc[mi][ni][r], x2 = acc[mi][ni + 4][r];
          dst[hb + ni * 16 + lq] = f2bf((x1 * cs - x2 * sn) * sc);
          dst[hb + ni * 16 + lq + 64] = f2bf((x2 * cs + x1 * sn) * sc);
        }
      }
  } else {
    const int hv = hx - 20;
    const int s00 = (m0 & (SDIM - 1)) + w * 32;
#pragma unroll
    for (int mi = 0; mi < 2; ++mi)
#pragma unroll
      for (int ni = 0; ni < 8; ++ni) {
        int d = ni * 16 + lq;
        int s0 = s00 + mi * 16 + 4 * g;
        size_t vb = ((size_t)(b * NKV + hv) * HD + d) * SDIM + s0;
        short4 ov;
        ov.x = f2bf(acc[mi][ni][0]); ov.y = f2bf(acc[mi][ni][1]);
        ov.z = f2bf(acc[mi][ni][2]); ov.w = f2bf(acc[mi][ni][3]);
        *(short4*)(VT + vb) = ov;
      }
  }
}

// ---- flash attention, causal GQA, INTRA-BLOCK kv-split x2 ----
// 512 threads = 8 waves: waves 0-3 = 4 q-subchunks x low kv half, waves 4-7 =
// same q x high kv half. Per-half double-buffered KVBLK=32 LDS staging (64KB).
// __launch_bounds__(512,2): 2 blocks/CU x 8 waves = 4 waves/SIMD at 128
// VGPRs/wave (NO spill — the (512,4) variant spilled to scratch and became
// scratch-BW-bound). Partials merged in LDS; hi waves write bf16 O~+(m,l),
// lo waves weight-combine exp2(mi-M). Per-tile body = verified round-6/10.
__global__ __launch_bounds__(512, 2) void k_attn(const short* __restrict__ Qh,
                                                 const short* __restrict__ Kh,
                                                 const short* __restrict__ VT,
                                                 short* __restrict__ attn, int S) {
  __shared__ char lds[65536];   // [sp][buf][16KB: K 8KB + V 8KB]; merge area reuses
  const int tid = threadIdx.x;
  const int w = tid >> 6, l = tid & 63;
  const int l31 = l & 31, hi = l >> 5;
  const int wq = w & 3;                     // q-subchunk
  const int sp = w >> 2;                    // kv half (0 lo, 1 hi)
  const int nqc = S / 128;                  // 16
  const int bid = blockIdx.x;
  const int b = bid / (NH * nqc);
  const int rem = bid % (NH * nqc);
  const int h = rem / nqc;
  const int qc = nqc - 1 - (rem % nqc);     // long blocks first
  const int q0 = qc * 128 + wq * 32;
  const int kvh = h >> 2;
  const short* Qp = Qh + (size_t)(b * NH + h) * S * HD;
  const short* Kp = Kh + (size_t)(b * NKV + kvh) * S * HD;
  const short* Vp = VT + (size_t)(b * NKV + kvh) * HD * S;
  char* base = lds + sp * 32768;

  // Q B-frags: col=l31=q, k = kc*16 + hi*8 + e
  bf16x8 qf[8];
#pragma unroll
  for (int kc = 0; kc < 8; ++kc)
    qf[kc] = *(const bf16x8*)(Qp + (size_t)(q0 + l31) * HD + kc * 16 + hi * 8);

  f32x16 o[4] = {};   // O^T block d0: row=d-rel=(r&3)+8*(r>>2)+4*hi, col=q=l31
  float mrun = -1e30f, lrun = 0.f;
  const int qabs = q0 + l31;
  const int halfT = qc * 2 + 2;             // 32-kv tiles per half (uniform)
  const int cbeg = sp * halfT;

  // STAGE by this half's 4 waves (256 threads): K 8KB (512 chunks) + V 8KB.
  // K [kr=id>>4][c16=id&15] swz c16^(kr&15); V [vr=id>>2][c4=id&3] swz
  // c4^((vr>>1)&3). LDS dest wave-uniform (rule #21).
#define STAGE(bufi, c0_)                                                          \
  {                                                                               \
    char* Kb = base + (bufi) * 16384;                                             \
    char* Vb = Kb + 8192;                                                         \
    _Pragma("unroll")                                                             \
    for (int i = 0; i < 2; ++i) {                                                 \
      int id = (i * 4 + wq) * 64 + l;                                             \
      int kr = id >> 4, c16 = id & 15;                                            \
      gload_lds16(Kp + (size_t)((c0_) + kr) * HD + ((c16 ^ (kr & 15)) * 8),       \
                  Kb + (i * 4 + wq) * 1024);                                      \
      int vr = id >> 2, c4 = id & 3;                                              \
      gload_lds16(Vp + (size_t)vr * S + (c0_) + ((c4 ^ ((vr >> 1) & 3)) * 8),     \
                  Vb + (i * 4 + wq) * 1024);                                      \
    }                                                                             \
  }

  STAGE(0, cbeg * 32);
  asm volatile("s_waitcnt vmcnt(0)" ::: "memory");
  __builtin_amdgcn_s_barrier();

  for (int t = 0; t < halfT; ++t) {
    const int c0 = (cbeg + t) * 32;
    const int cur = t & 1;
    if (t + 1 < halfT) STAGE(cur ^ 1, c0 + 32);
    const char* Ks = base + cur * 16384;
    const char* Vs = Ks + 8192;

    // --- QK^T from LDS (one 32-kv subtile) ---
    f32x16 st = {};
    __builtin_amdgcn_s_setprio(1);
#pragma unroll
    for (int kc = 0; kc < 8; ++kc) {
      bf16x8 kf = *(const bf16x8*)(Ks + l31 * 256 + (((kc * 2 + hi) ^ (l31 & 15)) * 16));
      st = __builtin_amdgcn_mfma_f32_32x32x16_bf16(kf, qf[kc], st, 0, 0, 0);
    }
    __builtin_amdgcn_s_setprio(0);
    // --- mask (boundary tiles only) + online softmax (log2 domain) ---
    float tmax = -1e30f;
    if (c0 + 32 <= q0) {                    // interior: no lane needs masking
#pragma unroll
      for (int r = 0; r < 16; ++r) tmax = fmaxf(tmax, st[r]);
    } else {
#pragma unroll
      for (int r = 0; r < 16; ++r) {
        int kv = c0 + (r & 3) + 8 * (r >> 2) + 4 * hi;
        float sv = (kv <= qabs) ? st[r] : -1e30f;
        st[r] = sv;
        tmax = fmaxf(tmax, sv);
      }
    }
    tmax = fmaxf(tmax, __shfl_xor(tmax, 32));
    if (!__all(tmax - mrun <= 8.0f)) {      // defer-max
      float mnew = fmaxf(mrun, tmax);
      float fac = exp2_fast(mrun - mnew);
      lrun *= fac;
#pragma unroll
      for (int d0 = 0; d0 < 4; ++d0) o[d0] = o[d0] * fac;
      mrun = mnew;
    }
    float sum = 0.f;
#pragma unroll
    for (int r = 0; r < 16; ++r) {
      float e = exp2_fast(st[r] - mrun);
      st[r] = e;
      sum += e;
    }
    sum += __shfl_xor(sum, 32);
    lrun += sum;
    // --- P -> B-frags (packed-word lane-half exchange) + PV from LDS V ---
    __builtin_amdgcn_s_setprio(1);
#pragma unroll
    for (int j = 0; j < 2; ++j) {
      uint32_t W0 = (uint32_t)(uint16_t)f2bf(st[8 * j + 0]) |
                    ((uint32_t)(uint16_t)f2bf(st[8 * j + 1]) << 16);
      uint32_t W1 = (uint32_t)(uint16_t)f2bf(st[8 * j + 2]) |
                    ((uint32_t)(uint16_t)f2bf(st[8 * j + 3]) << 16);
      uint32_t W2 = (uint32_t)(uint16_t)f2bf(st[8 * j + 4]) |
                    ((uint32_t)(uint16_t)f2bf(st[8 * j + 5]) << 16);
      uint32_t W3 = (uint32_t)(uint16_t)f2bf(st[8 * j + 6]) |
                    ((uint32_t)(uint16_t)f2bf(st[8 * j + 7]) << 16);
      uint32_t Y0 = __shfl_xor(hi ? W0 : W2, 32);
      uint32_t Y1 = __shfl_xor(hi ? W1 : W3, 32);
      union { uint32_t u[4]; bf16x8 v; } pu;
      pu.u[0] = hi ? Y0 : W0;
      pu.u[1] = hi ? Y1 : W1;
      pu.u[2] = hi ? W2 : Y0;
      pu.u[3] = hi ? W3 : Y1;
#pragma unroll
      for (int d0 = 0; d0 < 4; ++d0) {
        int vr = d0 * 32 + l31;
        bf16x8 vf = *(const bf16x8*)(Vs + vr * 64 + (((j * 2 + hi) ^ ((vr >> 1) & 3)) * 16));
        o[d0] = __builtin_amdgcn_mfma_f32_32x32x16_bf16(vf, pu.v, o[d0], 0, 0, 0);
      }
    }
    __builtin_amdgcn_s_setprio(0);
    asm volatile("s_waitcnt vmcnt(0)" ::: "memory");
    __builtin_amdgcn_s_barrier();
  }
#undef STAGE

  // ---- merge the two kv halves in LDS (KV buffers are dead now) ----
  // hi wave lane: 64 bf16 partials at wq*9216 + l*144 (16B-aligned chunks,
  // chunk k = d0*2+gh holds o[d0][gh*8..gh*8+7]); (m,l) f32 at 40960+.
  if (sp == 1) {
    char* ob = lds + wq * 9216 + l * 144;
#pragma unroll
    for (int d0 = 0; d0 < 4; ++d0)
#pragma unroll
      for (int gh = 0; gh < 2; ++gh) {
        short t8[8];
#pragma unroll
        for (int j = 0; j < 8; ++j) t8[j] = f2bf(o[d0][gh * 8 + j]);
        *(bf16x8*)(ob + (d0 * 2 + gh) * 16) = *(bf16x8*)t8;
      }
    if (hi == 0) {
      float2 t; t.x = mrun; t.y = lrun;
      *(float2*)(lds + 40960 + wq * 256 + l31 * 8) = t;
    }
  }
  __syncthreads();
  if (sp == 0) {
    float2 m2 = *(const float2*)(lds + 40960 + wq * 256 + l31 * 8);
    float M = fmaxf(mrun, m2.x);
    float a1 = exp2_fast(mrun - M), a2 = exp2_fast(m2.x - M);
    float denom = lrun * a1 + m2.y * a2;
    float f1 = a1 / denom, f2v = a2 / denom;
    const char* ob = lds + wq * 9216 + l * 144;
    size_t rowb = (size_t)(b * S + q0 + l31) * QSZ + h * HD;
#pragma unroll
    for (int d0 = 0; d0 < 4; ++d0)
#pragma unroll
      for (int gq = 0; gq < 4; ++gq) {      // drel group: 8*gq + 4*hi + (0..3)
        bf16x8 v2 = *(const bf16x8*)(ob + (d0 * 2 + (gq >> 1)) * 16);
        int e0 = (gq & 1) * 4;
        short4 ov;
        ov.x = f2bf(o[d0][4 * gq + 0] * f1 + bf2f(v2[e0 + 0]) * f2v);
        ov.y = f2bf(o[d0][4 * gq + 1] * f1 + bf2f(v2[e0 + 1]) * f2v);
        ov.z = f2bf(o[d0][4 * gq + 2] * f1 + bf2f(v2[e0 + 2]) * f2v);
        ov.w = f2bf(o[d0][4 * gq + 3] * f1 + bf2f(v2[e0 + 3]) * f2v);
        *(short4*)(attn + rowb + d0 * 32 + 8 * gq + 4 * hi) = ov;
      }
  }
}

extern "C" void kernel_launch(void* const* d_in, const int* in_sizes, int n_in,
                              void* d_out, int out_size, void* d_ws, size_t ws_size,
                              hipStream_t stream) {
  const int* positions = (const int*)d_in[0];
  const float* hidden = (const float*)d_in[1];
  const float* w_qkv = (const float*)d_in[2];
  const float* w_o = (const float*)d_in[3];
  float* out = (float*)d_out;

  char* ws = (char*)d_ws;
  short* X     = (short*)(ws);                    // 4096x2048 bf16
  short* WqkvT = (short*)(ws + 16777216);         // 3072x2048 bf16
  short* WoT   = (short*)(ws + 29360128);         // 2048x2048 bf16
  short* Qh    = (short*)(ws + 88080384);         // [2][16][2048][128]
  short* Kh    = (short*)(ws + 104857600);        // [2][4][2048][128]
  short* VT    = (short*)(ws + 109051904);        // [2][4][128][2048]
  short* ATT   = (short*)(ws + 113246208);        // [4096][2048] bf16

  k_cvt_bf16<<<8192, 256, 0, stream>>>(hidden, X, TOK * HID);
  k_transpose_cvt<<<dim3(QKVW / 64, HID / 64), 256, 0, stream>>>(w_qkv, WqkvT, HID, QKVW);
  k_transpose_cvt<<<dim3(HID / 64, QSZ / 64), 256, 0, stream>>>(w_o, WoT, QSZ, HID);
  k_gemm_qkv_rope<<<dim3(QKVW / 128, TOK / 128), 256, 0, stream>>>(X, WqkvT, positions,
                                                                   Qh, Kh, VT);
  k_attn<<<BDIM * NH * (SDIM / 128), 512, 0, stream>>>(Qh, Kh, VT, ATT, SDIM);
  k_gemm_bf16<<<dim3(HID / 128, TOK / 128), 256, 0, stream>>>(ATT, WoT, out, TOK, HID, QSZ);
}